// Round 4
// baseline (378.039 us; speedup 1.0000x reference)
//
#include <hip/hip_runtime.h>
#include <math.h>

#define LEAKY 0.01f

using short8 = __attribute__((ext_vector_type(8))) short;
using f32x4  = __attribute__((ext_vector_type(4))) float;

__device__ __forceinline__ ushort f2bf(float f) {
  uint u = __float_as_uint(f);
  uint r = (u + 0x7FFFu + ((u >> 16) & 1u)) >> 16;
  return (ushort)r;
}
__device__ __forceinline__ float bf2f(ushort h) {
  uint u = ((uint)h) << 16;
  return __uint_as_float(u);
}

// ---------------- degree / CSR build ----------------

__global__ void k_zero_i(int* __restrict__ p, int n) {
  int i = blockIdx.x * blockDim.x + threadIdx.x;
  if (i < n) p[i] = 0;
}

__global__ void k_count(const int* __restrict__ dst, int* __restrict__ cnt, int E) {
  int i = blockIdx.x * blockDim.x + threadIdx.x;
  if (i < E) atomicAdd(&cnt[dst[i]], 1);
}

__global__ void k_dinv(const int* __restrict__ cnt, float* __restrict__ dinv, int N) {
  int i = blockIdx.x * blockDim.x + threadIdx.x;
  if (i < N) dinv[i] = rsqrtf((float)cnt[i] + 1.0f);
}

// single block, 1024 threads; N <= 16384. cursor is a SEPARATE buffer (no aliasing).
__global__ void k_scan(const int* __restrict__ cnt, int* __restrict__ rowstart,
                       int* __restrict__ cursor, int N, int Etot) {
  __shared__ int part[1024];
  const int t = threadIdx.x;
  const int CH = 16;
  int base = t * CH;
  int local[CH];
  int s = 0;
#pragma unroll
  for (int i = 0; i < CH; i++) {
    int v = (base + i < N) ? cnt[base + i] : 0;
    local[i] = s;
    s += v;
  }
  part[t] = s;
  __syncthreads();
  for (int off = 1; off < 1024; off <<= 1) {
    int add = (t >= off) ? part[t - off] : 0;
    __syncthreads();
    part[t] += add;
    __syncthreads();
  }
  int excl = (t == 0) ? 0 : part[t - 1];
#pragma unroll
  for (int i = 0; i < CH; i++) {
    if (base + i < N) {
      int rs = excl + local[i];
      rowstart[base + i] = rs;
      cursor[base + i] = rs;
    }
  }
  if (t == 0) rowstart[N] = Etot;
}

__global__ void k_csr(const int* __restrict__ src, const int* __restrict__ dst,
                      int* __restrict__ cursor, int* __restrict__ esrc, int E) {
  int i = blockIdx.x * blockDim.x + threadIdx.x;
  if (i < E) {
    int d = dst[i];
    int pos = atomicAdd(&cursor[d], 1);
    esrc[pos] = src[i];
  }
}

// ---------------- fp32 -> 3K split bf16 ----------------
// A-side rows: [hi | hi | lo]   (length 3K)
__global__ void k_split_rows3(const float* __restrict__ in, ushort* __restrict__ out,
                              long total, int K) {
  long i = (long)blockIdx.x * blockDim.x + threadIdx.x;
  if (i < total) {
    long m = i / K;
    int k = (int)(i % K);
    float v = in[i];
    ushort hi = f2bf(v);
    ushort lo = f2bf(v - bf2f(hi));
    ushort* row = out + m * 3 * K;
    row[k] = hi;
    row[K + k] = hi;
    row[2 * K + k] = lo;
  }
}

// B-side: W [K,N] f32 -> Wt3 [N,3K]: [hi | lo | hi]  (transpose + split)
__global__ void k_split_wt3(const float* __restrict__ W, ushort* __restrict__ Wt3,
                            int K, int N) {
  int i = blockIdx.x * blockDim.x + threadIdx.x;
  if (i < K * N) {
    int k = i / N;
    int n = i % N;
    float v = W[i];
    ushort hi = f2bf(v);
    ushort lo = f2bf(v - bf2f(hi));
    ushort* row = Wt3 + (long)n * 3 * K;
    row[k] = hi;
    row[K + k] = lo;
    row[2 * K + k] = hi;
  }
}

// ---------------- gather aggregation (no atomics) ----------------
// one wave per node; F = VL*64 features
// SPLIT: write A-side 3K split bf16 [N,3F] (leaky'd) for next MFMA layer
// LAST:  write fp32 h to outh and plain bf16 to hb
template <int F, int VL, bool SPLIT, bool LAST>
__global__ __launch_bounds__(64) void k_agg(const float* __restrict__ hlin,
                                            const float* __restrict__ dinv,
                                            const int* __restrict__ rowstart,
                                            const int* __restrict__ esrc,
                                            const float* __restrict__ bias,
                                            ushort* __restrict__ aggb,
                                            float* __restrict__ outh,
                                            ushort* __restrict__ hb, int N) {
  const int node = blockIdx.x;
  const int t = threadIdx.x;
  const float di = dinv[node];
  float acc[VL];
  {
    const float* p = hlin + (long)node * F + t * VL;
    if (VL == 4) {
      float4 v = *reinterpret_cast<const float4*>(p);
      acc[0] = v.x; acc[1] = v.y; acc[2] = v.z; acc[3] = v.w;
    } else {
      float2 v = *reinterpret_cast<const float2*>(p);
      acc[0] = v.x; acc[1] = v.y;
    }
#pragma unroll
    for (int i = 0; i < VL; i++) acc[i] *= di * di;
  }
  const int e0 = rowstart[node], e1 = rowstart[node + 1];
  int e = e0;
  for (; e + 1 < e1; e += 2) {
    int s0 = esrc[e], s1 = esrc[e + 1];
    float nm0 = dinv[s0] * di, nm1 = dinv[s1] * di;
    const float* p0 = hlin + (long)s0 * F + t * VL;
    const float* p1 = hlin + (long)s1 * F + t * VL;
    if (VL == 4) {
      float4 v0 = *reinterpret_cast<const float4*>(p0);
      float4 v1 = *reinterpret_cast<const float4*>(p1);
      acc[0] += v0.x * nm0 + v1.x * nm1;
      acc[1] += v0.y * nm0 + v1.y * nm1;
      acc[2] += v0.z * nm0 + v1.z * nm1;
      acc[3] += v0.w * nm0 + v1.w * nm1;
    } else {
      float2 v0 = *reinterpret_cast<const float2*>(p0);
      float2 v1 = *reinterpret_cast<const float2*>(p1);
      acc[0] += v0.x * nm0 + v1.x * nm1;
      acc[1] += v0.y * nm0 + v1.y * nm1;
    }
  }
  if (e < e1) {
    int s0 = esrc[e];
    float nm0 = dinv[s0] * di;
    const float* p0 = hlin + (long)s0 * F + t * VL;
    if (VL == 4) {
      float4 v0 = *reinterpret_cast<const float4*>(p0);
      acc[0] += v0.x * nm0; acc[1] += v0.y * nm0;
      acc[2] += v0.z * nm0; acc[3] += v0.w * nm0;
    } else {
      float2 v0 = *reinterpret_cast<const float2*>(p0);
      acc[0] += v0.x * nm0; acc[1] += v0.y * nm0;
    }
  }
#pragma unroll
  for (int i = 0; i < VL; i++) {
    float v = acc[i] + bias[t * VL + i];
    v = (v > 0.f) ? v : (LEAKY * v);
    int f = t * VL + i;
    if (SPLIT) {
      ushort hi = f2bf(v);
      ushort lo = f2bf(v - bf2f(hi));
      ushort* row = aggb + (long)node * 3 * F;
      row[f] = hi;
      row[F + f] = hi;
      row[2 * F + f] = lo;
    }
    if (LAST) {
      long idx = (long)node * F + f;
      outh[idx] = v;
      hb[idx] = f2bf(v);
    }
  }
}

// ---------------- bf16 MFMA GEMM-BT: C[M,N] = A[M,K] * B[N,K]^T ----------------
// A,B bf16 row-major, K multiple of 128. 128x128 tile, 4 waves.
// EPI 0: plain fp32 store. EPI 1: sigmoid + nontemporal store.
template <int EPI>
__global__ __launch_bounds__(256) void k_gemm_bt(const ushort* __restrict__ Ab,
                                                 const ushort* __restrict__ Bb,
                                                 float* __restrict__ C,
                                                 int M, int N, int K, int ldc) {
  __shared__ ushort lds[2 * 128 * 128];  // A tile 32KB + B tile 32KB, XOR-swizzled
  ushort* ldsA = lds;
  ushort* ldsB = lds + 128 * 128;

  const int tid = threadIdx.x;
  const int lane = tid & 63;
  const int wv = tid >> 6;
  const int wr = wv >> 1, wc = wv & 1;
  const long bm = (long)blockIdx.y * 128;
  const long bn = (long)blockIdx.x * 128;

  f32x4 acc[4][4];
#pragma unroll
  for (int i = 0; i < 4; i++)
#pragma unroll
    for (int j = 0; j < 4; j++) acc[i][j] = (f32x4){0.f, 0.f, 0.f, 0.f};

  const int kb = ((lane >> 4) << 4);

  for (int k0 = 0; k0 < K; k0 += 128) {
#pragma unroll
    for (int t = 0; t < 2; t++) {
      long rbase = t ? bn : bm;
      long rmax = (long)(t ? N : M) - 1;
      const ushort* G = t ? Bb : Ab;
      ushort* L = t ? ldsB : ldsA;
#pragma unroll
      for (int it = 0; it < 8; it++) {
        int off = it * 4096 + tid * 16;  // byte offset in 32KB tile
        int row = off >> 8;
        int cb = off & 255;
        long grow = rbase + row;
        uint4 v = make_uint4(0u, 0u, 0u, 0u);
        if (grow <= rmax)
          v = *reinterpret_cast<const uint4*>(&G[grow * K + k0 + (cb >> 1)]);
        int sb = (row << 8) | (cb ^ ((row & 7) << 4));
        *reinterpret_cast<uint4*>((char*)L + sb) = v;
      }
    }
    __syncthreads();

#pragma unroll
    for (int ks = 0; ks < 4; ks++) {
      short8 af[4], bfr[4];
#pragma unroll
      for (int mi = 0; mi < 4; mi++) {
        int row = wr * 64 + mi * 16 + (lane & 15);
        int b = ks * 64 + kb;
        int addr = (row << 8) | (b ^ ((row & 7) << 4));
        af[mi] = *reinterpret_cast<const short8*>((const char*)ldsA + addr);
      }
#pragma unroll
      for (int ni = 0; ni < 4; ni++) {
        int row = wc * 64 + ni * 16 + (lane & 15);
        int b = ks * 64 + kb;
        int addr = (row << 8) | (b ^ ((row & 7) << 4));
        bfr[ni] = *reinterpret_cast<const short8*>((const char*)ldsB + addr);
      }
#pragma unroll
      for (int mi = 0; mi < 4; mi++)
#pragma unroll
        for (int ni = 0; ni < 4; ni++)
          acc[mi][ni] = __builtin_amdgcn_mfma_f32_16x16x32_bf16(af[mi], bfr[ni], acc[mi][ni], 0, 0, 0);
    }
    __syncthreads();
  }

  // epilogue: C frag layout col=lane&15, row=(lane>>4)*4+reg
#pragma unroll
  for (int ni = 0; ni < 4; ni++) {
    long col = bn + wc * 64 + ni * 16 + (lane & 15);
    if (col >= N) continue;
#pragma unroll
    for (int mi = 0; mi < 4; mi++) {
      long rbase2 = bm + wr * 64 + mi * 16 + ((lane >> 4) << 2);
#pragma unroll
      for (int j = 0; j < 4; j++) {
        long row = rbase2 + j;
        if (row >= M) continue;
        float v = acc[mi][ni][j];
        if (EPI == 1) {
          v = 1.f / (1.f + __expf(-v));
          __builtin_nontemporal_store(v, &C[row * ldc + col]);
        } else {
          C[row * ldc + col] = v;
        }
      }
    }
  }
}

// ---------------- launch ----------------

extern "C" void kernel_launch(void* const* d_in, const int* in_sizes, int n_in,
                              void* d_out, int out_size, void* d_ws, size_t ws_size,
                              hipStream_t stream) {
  const float* x  = (const float*)d_in[0];
  const int*   ei = (const int*)d_in[1];
  const float* W1 = (const float*)d_in[3];
  const float* b1 = (const float*)d_in[4];
  const float* W2 = (const float*)d_in[5];
  const float* b2 = (const float*)d_in[6];

  const int N   = in_sizes[2];          // 10000
  const int E   = in_sizes[1] / 2;      // 320000
  const int Fin = in_sizes[0] / N;      // 512
  const int F1  = in_sizes[4];          // 256
  const int F2  = in_sizes[6];          // 128

  const int* src = ei;
  const int* dst = ei + E;

  float* ws = (float*)d_ws;
  ushort* x3       = (ushort*)ws;                    // N*3*Fin ush = 7,680,000 f
  ushort* w1t3     = (ushort*)(ws + 7680000);        // F1*3*Fin ush = 196,608 f
  float*  h1lin    = ws + 7876608;                   // N*F1 f = 2,560,000
  ushort* agg1b3   = (ushort*)(ws + 10436608);       // N*3*F1 ush = 3,840,000 f
  ushort* w2t3     = (ushort*)(ws + 14276608);       // F2*3*F1 ush = 49,152 f
  float*  h2lin    = ws + 14325760;                  // N*F2 f = 1,280,000
  ushort* hb       = (ushort*)(ws + 15605760);       // N*F2 ush = 320,000 f
  float*  dinv     = ws + 16245760;                  // N (pad 10240)
  int*    cnt      = (int*)(ws + 16256000);          // N
  int*    cursor   = (int*)(ws + 16266240);          // N
  int*    rowstart = (int*)(ws + 16276480);          // N+1
  int*    esrc     = (int*)(ws + 16286976);          // E

  float* out_x1 = (float*)d_out;
  float* out_h  = out_x1 + (long)N * N;

  // CSR build + dinv
  k_zero_i<<<(N + 255) / 256, 256, 0, stream>>>(cnt, N);
  k_count<<<(E + 255) / 256, 256, 0, stream>>>(dst, cnt, E);
  k_dinv<<<(N + 255) / 256, 256, 0, stream>>>(cnt, dinv, N);
  k_scan<<<1, 1024, 0, stream>>>(cnt, rowstart, cursor, N, E);
  k_csr<<<(E + 255) / 256, 256, 0, stream>>>(src, dst, cursor, esrc, E);

  // split conversions
  {
    long tot = (long)N * Fin;
    k_split_rows3<<<(unsigned)((tot + 255) / 256), 256, 0, stream>>>(x, x3, tot, Fin);
    k_split_wt3<<<(Fin * F1 + 255) / 256, 256, 0, stream>>>(W1, w1t3, Fin, F1);
    k_split_wt3<<<(F1 * F2 + 255) / 256, 256, 0, stream>>>(W2, w2t3, F1, F2);
  }

  // layer 1: h1lin = x @ W1   (3K split-bf16 MFMA, K' = 3*Fin = 1536)
  {
    dim3 grid(F1 / 128, (N + 127) / 128);
    k_gemm_bt<0><<<grid, 256, 0, stream>>>(x3, w1t3, h1lin, N, F1, 3 * Fin, F1);
  }
  k_agg<256, 4, true, false><<<N, 64, 0, stream>>>(h1lin, dinv, rowstart, esrc, b1,
                                                   agg1b3, nullptr, nullptr, N);

  // layer 2: h2lin = h1 @ W2  (3K split-bf16 MFMA, K' = 3*F1 = 768)
  {
    dim3 grid(F2 / 128, (N + 127) / 128);
    k_gemm_bt<0><<<grid, 256, 0, stream>>>(agg1b3, w2t3, h2lin, N, F2, 3 * F1, F2);
  }
  k_agg<128, 2, false, true><<<N, 64, 0, stream>>>(h2lin, dinv, rowstart, esrc, b2,
                                                   nullptr, out_h, hb, N);

  // decode: x1 = sigmoid(h @ h^T)
  {
    dim3 grid((N + 127) / 128, (N + 127) / 128);
    k_gemm_bt<1><<<grid, 256, 0, stream>>>(hb, hb, out_x1, N, N, F2, N);
  }
}